// Round 4
// baseline (248.200 us; speedup 1.0000x reference)
//
#include <hip/hip_runtime.h>
#include <math.h>

#define KCODES 2048
#define DIM 64
#define NROWS 65536          // 64*32*32
#define NELEM (NROWS * DIM)  // 4194304

// ws layout (bytes):
//   0      .. 8191   : hist[2048] (int)
//   8192   .. 16383  : c2[2048]  (float)  exact col norms (fixup uses)
//   16384  .. 24575  : c2s[2048] (float)  (c2+64)*16384   (MFMA C-operand bias)
//   24576  .. 24579  : sse (float)
//   24580  .. 24583  : done (int)         last-block counter
//   32768  .. 557055 : P — prepacked B-fragments of (-2*codebook), bf16 hi/lo.
//     chunk id bits [t16:7][p:1][s:1][q:2][c:4], 16 B per chunk:
//     chunk(id) = 8 bf16 of code (t16*16+c), dims s*32+q*8 .. +8, plane p (0=hi,1=lo)
//     => lane (c,q) of a wave loads its 16x16x32-MFMA B-fragment at base+lane*16.
#define WS_HIST 0
#define WS_C2   8192
#define WS_C2S  16384
#define WS_SSE  24576
#define WS_DONE 24580
#define WS_P    32768

#define EPS_PK 33        // margin threshold in 2^-14 dist units = 2.01e-3

typedef float  floatx4 __attribute__((ext_vector_type(4)));
typedef short  short8  __attribute__((ext_vector_type(8)));

__device__ __forceinline__ unsigned short f2bf(float f) {
  union { float f; unsigned u; } a; a.f = f;
  unsigned r = (a.u + 0x7FFFu + ((a.u >> 16) & 1u)) >> 16;  // RNE, finite inputs
  return (unsigned short)r;
}
__device__ __forceinline__ float bf2f(unsigned short h) {
  union { unsigned u; float f; } a; a.u = ((unsigned)h) << 16;
  return a.f;
}
__device__ __forceinline__ unsigned umin2(unsigned a, unsigned b) { return a < b ? a : b; }
__device__ __forceinline__ unsigned umax2(unsigned a, unsigned b) { return a > b ? a : b; }

// Fused prep: pack one 16B B-fragment chunk per thread; threads with id<2048
// also produce c2/c2s and zero hist/sse/done. 128 blocks x 256 thr.
__global__ void vq_prep(const float* __restrict__ cb, char* __restrict__ P,
                        float* __restrict__ c2, float* __restrict__ c2s,
                        int* __restrict__ hist, float* __restrict__ sse,
                        int* __restrict__ done) {
  const int id = blockIdx.x * 256 + threadIdx.x;   // 0..32767
  const int c   = id & 15;
  const int q   = (id >> 4) & 3;
  const int s   = (id >> 6) & 1;
  const int p   = (id >> 7) & 1;
  const int t16 = id >> 8;
  const int code = t16 * 16 + c;
  const int d0 = s * 32 + q * 8;
  short8 o;
#pragma unroll
  for (int e = 0; e < 8; ++e) {
    float v = -2.0f * cb[(size_t)(d0 + e) * KCODES + code];
    unsigned short hb = f2bf(v);
    float lo = v - bf2f(hb);
    o[e] = p ? (short)f2bf(lo) : (short)hb;
  }
  *(short8*)(P + (size_t)id * 16) = o;

  if (id < KCODES) {
    float ss = 0.f;
#pragma unroll
    for (int d = 0; d < DIM; ++d) {
      float v = cb[d * KCODES + id];
      ss = fmaf(v, v, ss);
    }
    c2[id] = ss;                       // exact round-1 order (fixup relies on it)
    c2s[id] = (ss + 64.0f) * 16384.0f;
    hist[id] = 0;
    if (id == 0) { *sse = 0.f; *done = 0; }
  }
}

// Block = 256 thr = 4 waves: wave (rg, ch) owns rows rg*64..+64, codes ch*1024..+1024.
// Barrier-free K-loop: B-fragments loaded straight from L2-resident P (register
// double-buffer, one 32-code tile of prefetch), bias folded into MFMA C operand,
// packed-uint argmin with second-best margin; exact fp32 fixup for near-ties;
// fused epilogue + last-block finalization (perplexity/losses).
__global__ __launch_bounds__(256, 2) void vq_main(
    const float* __restrict__ inp, const float* __restrict__ cb,
    const float* __restrict__ c2, const float* __restrict__ c2s,
    const char* __restrict__ P, int* __restrict__ hist,
    float* __restrict__ sse, int* __restrict__ done, float* __restrict__ out)
{
  __shared__ unsigned s_m1[2][128], s_m2[2][128];
  __shared__ int   s_k[128];
  __shared__ int   s_nflag;
  __shared__ int   s_frows[128];
  __shared__ float s_rd[256];
  __shared__ int   s_rk[256];
  __shared__ float s_red[4];
  __shared__ int   s_last;

  const int t    = threadIdx.x;
  const int lane = t & 63;
  const int wave = __builtin_amdgcn_readfirstlane(t >> 6);
  const int rg   = wave & 1;    // row-group within block
  const int ch   = wave >> 1;   // code-half
  const int c    = lane & 15;   // MFMA column (code within 16)
  const int q    = lane >> 4;   // MFMA quad (dim group)
  const int rowbase = blockIdx.x * 128 + rg * 64;

  if (t == 0) s_nflag = 0;

  // ---- A fragments: 64 rows, x*2^14 split to bf16 hi/lo; [rowtile][kstep] ----
  short8 Ah[4][2], Al[4][2];
#pragma unroll
  for (int rt = 0; rt < 4; ++rt) {
#pragma unroll
    for (int s = 0; s < 2; ++s) {
      const float* px = inp + (size_t)(rowbase + rt * 16 + c) * 64 + s * 32 + q * 8;
      float4 u0 = *(const float4*)px;
      float4 u1 = *(const float4*)(px + 4);
      float u[8] = {u0.x, u0.y, u0.z, u0.w, u1.x, u1.y, u1.z, u1.w};
      short8 hh, ll;
#pragma unroll
      for (int e = 0; e < 8; ++e) {
        float xs = u[e] * 16384.0f;          // exact pow2 scale
        unsigned short hb = f2bf(xs);
        float lo = xs - bf2f(hb);
        hh[e] = (short)hb;
        ll[e] = (short)f2bf(lo);
      }
      Ah[rt][s] = hh; Al[rt][s] = ll;
    }
  }

  unsigned d1[16], d2[16];
#pragma unroll
  for (int i = 0; i < 16; ++i) { d1[i] = 0xFFFFFFFFu; d2[i] = 0xFFFFFFFFu; }

  const char* Pw = P + ((size_t)ch << 18);           // code-half base (256 KB)
  const float* c2sw = c2s + ch * 1024;

  // frag index f = p*2+s: 0=bh0 1=bh1 2=bl0 3=bl1
  auto load_tile = [&](short8 B[2][4], int j) {
#pragma unroll
    for (int nt = 0; nt < 2; ++nt)
#pragma unroll
      for (int f = 0; f < 4; ++f)
        B[nt][f] = *(const short8*)(Pw + ((((j * 2 + nt) * 4 + f) << 10) + lane * 16));
  };

  auto comp_tile = [&](short8 B[2][4], int j) {
#pragma unroll
    for (int nt = 0; nt < 2; ++nt) {
      float c2v = c2sw[j * 32 + nt * 16 + c];
      floatx4 ci = {c2v, c2v, c2v, c2v};
      floatx4 acc[4];
      // 6-term chain per rowtile, interleaved for MFMA ILP; bias rides in C.
#pragma unroll
      for (int rt = 0; rt < 4; ++rt)
        acc[rt] = __builtin_amdgcn_mfma_f32_16x16x32_bf16(Al[rt][1], B[nt][1], ci, 0, 0, 0);
#pragma unroll
      for (int rt = 0; rt < 4; ++rt)
        acc[rt] = __builtin_amdgcn_mfma_f32_16x16x32_bf16(Ah[rt][1], B[nt][3], acc[rt], 0, 0, 0);
#pragma unroll
      for (int rt = 0; rt < 4; ++rt)
        acc[rt] = __builtin_amdgcn_mfma_f32_16x16x32_bf16(Al[rt][0], B[nt][0], acc[rt], 0, 0, 0);
#pragma unroll
      for (int rt = 0; rt < 4; ++rt)
        acc[rt] = __builtin_amdgcn_mfma_f32_16x16x32_bf16(Ah[rt][0], B[nt][2], acc[rt], 0, 0, 0);
#pragma unroll
      for (int rt = 0; rt < 4; ++rt)
        acc[rt] = __builtin_amdgcn_mfma_f32_16x16x32_bf16(Ah[rt][1], B[nt][1], acc[rt], 0, 0, 0);
#pragma unroll
      for (int rt = 0; rt < 4; ++rt)
        acc[rt] = __builtin_amdgcn_mfma_f32_16x16x32_bf16(Ah[rt][0], B[nt][0], acc[rt], 0, 0, 0);
      const unsigned kcn = ch * 1024 + j * 32 + nt * 16 + c;
#pragma unroll
      for (int rt = 0; rt < 4; ++rt)
#pragma unroll
        for (int reg = 0; reg < 4; ++reg) {
          unsigned u = (((unsigned)acc[rt][reg]) << 11) + kcn;  // S*(dist+64) > 0
          const int i = rt * 4 + reg;
          d2[i] = umin2(d2[i], umax2(d1[i], u));
          d1[i] = umin2(d1[i], u);
        }
    }
  };

  short8 BA[2][4], BB[2][4];
  load_tile(BA, 0);
#pragma unroll 1
  for (int j = 0; j < 32; j += 2) {
    load_tile(BB, j + 1);
    comp_tile(BA, j);
    if (j + 2 < 32) load_tile(BA, j + 2);
    comp_tile(BB, j + 1);
  }

  // ---- cross-lane argmin reduce over 16 code-columns (packed-uint min) ----
#pragma unroll
  for (int i = 0; i < 16; ++i) {
    unsigned D1 = d1[i], D2 = d2[i];
#pragma unroll
    for (int off = 1; off < 16; off <<= 1) {
      unsigned o1 = (unsigned)__shfl_xor((int)D1, off, 64);
      unsigned o2 = (unsigned)__shfl_xor((int)D2, off, 64);
      D2 = umin2(umin2(D2, o2), umax2(D1, o1));
      D1 = umin2(D1, o1);
    }
    if (c == 0) {
      int lr = rg * 64 + (i >> 2) * 16 + q * 4 + (i & 3);
      s_m1[ch][lr] = D1;
      s_m2[ch][lr] = D2;
    }
  }
  __syncthreads();

  // ---- merge the two code-halves per row ----
  if (t < 128) {
    unsigned a1 = s_m1[0][t], a2 = s_m2[0][t];
    unsigned b1 = s_m1[1][t], b2 = s_m2[1][t];
    unsigned D1 = umin2(a1, b1);
    unsigned D2 = umin2(umin2(a2, b2), umax2(a1, b1));
    s_k[t] = (int)(D1 & 2047u);
    if ((int)((D2 >> 11) - (D1 >> 11)) < EPS_PK) {
      int idx = atomicAdd(&s_nflag, 1);
      s_frows[idx] = t;
    }
  }
  __syncthreads();

  // ---- exact fp32 fixup for near-tie rows (round-1 arithmetic, proven) ----
  const int nf = s_nflag;
  for (int f = 0; f < nf; ++f) {
    const int lrow = s_frows[f];
    const float* xr = inp + (size_t)(blockIdx.x * 128 + lrow) * 64;
    float xs[64];
    float x2 = 0.f;
#pragma unroll
    for (int i = 0; i < 16; ++i) {
      float4 v = *(const float4*)(xr + i * 4);
      xs[4 * i + 0] = v.x; xs[4 * i + 1] = v.y; xs[4 * i + 2] = v.z; xs[4 * i + 3] = v.w;
      x2 = fmaf(v.x, v.x, x2); x2 = fmaf(v.y, v.y, x2);
      x2 = fmaf(v.z, v.z, x2); x2 = fmaf(v.w, v.w, x2);
    }
    float dot[8];
#pragma unroll
    for (int cc = 0; cc < 8; ++cc) dot[cc] = 0.f;
    const float* cp = cb + t * 8;
#pragma unroll 4
    for (int d = 0; d < 64; ++d) {
      float xd = xs[d];
#pragma unroll
      for (int cc = 0; cc < 8; ++cc)
        dot[cc] = fmaf(xd, cp[(size_t)d * KCODES + cc], dot[cc]);
    }
    float bd = INFINITY; int bk = 0;
#pragma unroll
    for (int cc = 0; cc < 8; ++cc) {
      float dd = (x2 - 2.0f * dot[cc]) + c2[t * 8 + cc];
      if (dd < bd) { bd = dd; bk = t * 8 + cc; }
    }
    s_rd[t] = bd; s_rk[t] = bk;
    __syncthreads();
    for (int s = 128; s >= 1; s >>= 1) {
      if (t < s) {
        if (s_rd[t + s] < s_rd[t]) { s_rd[t] = s_rd[t + s]; s_rk[t] = s_rk[t + s]; }
      }
      __syncthreads();
    }
    if (t == 0) s_k[lrow] = s_rk[0];
    __syncthreads();
  }

  if (t < 128) atomicAdd(&hist[s_k[t]], 1);

  // ---- epilogue: gather q, STE write, SSE ----
  const int fr = t >> 1;
  const int fd = (t & 1) * 32;
  const int grow = blockIdx.x * 128 + fr;
  const int myk = s_k[fr];
  const float* xrow = inp + (size_t)grow * 64 + fd;
  float* orow = out + (size_t)grow * 64 + fd;
  float serr = 0.f;
#pragma unroll
  for (int i = 0; i < 32; ++i) {
    float xv = xrow[i];
    float qv = cb[(size_t)(fd + i) * KCODES + myk];
    float dq = qv - xv;
    serr = fmaf(dq, dq, serr);
    orow[i] = xv + dq;
  }
#pragma unroll
  for (int off = 32; off > 0; off >>= 1) serr += __shfl_down(serr, off, 64);
  if (lane == 0) s_red[wave] = serr;
  __syncthreads();
  if (t == 0) atomicAdd(sse, s_red[0] + s_red[1] + s_red[2] + s_red[3]);

  // ---- last-block finalization (device-scope counter) ----
  __threadfence();
  if (t == 0) s_last = (atomicAdd(done, 1) == (int)gridDim.x - 1);
  __syncthreads();
  if (s_last) {
    float s = 0.f;
    for (int k = t; k < KCODES; k += 256) {
      int h = atomicAdd(&hist[k], 0);                 // device-scope read
      float pp = (float)h * (1.0f / NROWS);
      s += pp * logf(pp + 1e-10f);
    }
#pragma unroll
    for (int off = 32; off > 0; off >>= 1) s += __shfl_down(s, off, 64);
    if (lane == 0) s_red[wave] = s;
    __syncthreads();
    if (t == 0) {
      float tot = s_red[0] + s_red[1] + s_red[2] + s_red[3];
      out[NELEM] = expf(-tot);                        // perplexity
      float cl = atomicAdd(sse, 0.0f) * (1.0f / NELEM);
      out[NELEM + 1] = cl;                            // codebook_loss
      out[NELEM + 2] = 0.25f * cl;                    // commitment_loss
    }
  }
}

extern "C" void kernel_launch(void* const* d_in, const int* in_sizes, int n_in,
                              void* d_out, int out_size, void* d_ws, size_t ws_size,
                              hipStream_t stream) {
  const float* inp = (const float*)d_in[0];
  const float* cb  = (const float*)d_in[1];
  float* out = (float*)d_out;
  char* ws = (char*)d_ws;
  int*   hist = (int*)(ws + WS_HIST);
  float* c2   = (float*)(ws + WS_C2);
  float* c2s  = (float*)(ws + WS_C2S);
  float* sse  = (float*)(ws + WS_SSE);
  int*   done = (int*)(ws + WS_DONE);
  char*  P    = ws + WS_P;

  vq_prep<<<128, 256, 0, stream>>>(cb, P, c2, c2s, hist, sse, done);
  vq_main<<<NROWS / 128, 256, 0, stream>>>(inp, cb, c2, c2s, P, hist, sse, done, out);
}